// Round 1
// baseline (1631.016 us; speedup 1.0000x reference)
//
#include <hip/hip_runtime.h>
#include <math.h>

#define TPB 256

// ---------------- workspace layout (bytes) ----------------
constexpr size_t OFF_COUNTS   = 0x000000; // 64 ints: [0..8]=ccount,[16..24]=scount,[32..40]=c128,[48..56]=s128
constexpr size_t OFF_ACTIVE   = 0x000100; // 1 int
constexpr size_t OFF_SSUM     = 0x000200; // float ssum[9][256]
constexpr size_t OFF_SMEAN    = 0x002800; // float sMeanArr[10][256]
constexpr size_t OFF_MU       = 0x005000; // float mu[64]
constexpr size_t OFF_W1T      = 0x005200; // 1728 f  [27][64]
constexpr size_t OFF_W3T      = 0x007000; // 4608 f  [288][16]
constexpr size_t OFF_W2T      = 0x00C000; // 18432 f [576][32]
constexpr size_t OFF_POOLED   = 0x020000; // float [2][9][4096]
constexpr size_t OFF_M        = 0x068000; // float [2][9][4096]
constexpr size_t OFF_T        = 0x0B0000; // float [10][64][64]
constexpr size_t OFF_CBITS    = 0x0E0000; // int[65536]
constexpr size_t OFF_SBITS    = 0x120000; // int[65536]
constexpr size_t OFF_CBITS128 = 0x160000; // int[16384]
constexpr size_t OFF_SBITS128 = 0x170000; // int[16384]
constexpr size_t OFF_IDX      = 0x180000; // int [2][9][16384]
constexpr size_t OFF_RMAP     = 0x2A0000; // int[65536]
constexpr size_t OFF_XC       = 0x300000;  // float [64][65536]
constexpr size_t OFF_TRANS    = 0x1300000; // float [64][65536]
constexpr size_t OFF_F1       = 0x2300000; // float [64][512][512]
constexpr size_t OFF_F2       = 0x6300000; // float [32][256][256]
constexpr size_t OFF_F3       = 0x6B00000; // float [16][128][128]

// ---------------- small init ----------------
__global__ void init_k(int* p, int n) {
    for (int i = blockIdx.x * TPB + threadIdx.x; i < n; i += gridDim.x * TPB) p[i] = 0;
}

// ---------------- mask bit planes + counts ----------------
__global__ void bits_k(const int* __restrict__ cm, const int* __restrict__ sm,
                       int* __restrict__ cbits, int* __restrict__ sbits, int* __restrict__ counts) {
    int p = blockIdx.x * TPB + threadIdx.x;   // 65536
    int cb = 0, sb = 0;
#pragma unroll
    for (int r = 0; r < 9; ++r) {
        cb |= (cm[r * 65536 + p] == 1) << r;
        sb |= (sm[r * 65536 + p] == 1) << r;
    }
    cbits[p] = cb; sbits[p] = sb;
    int lane = threadIdx.x & 63;
#pragma unroll
    for (int r = 0; r < 9; ++r) {
        unsigned long long b1 = __ballot((cb >> r) & 1);
        if (lane == 0) atomicAdd(&counts[0 + r], __popcll(b1));
        unsigned long long b2 = __ballot((sb >> r) & 1);
        if (lane == 0) atomicAdd(&counts[16 + r], __popcll(b2));
    }
}

__global__ void bits128_k(const int* __restrict__ cm, const int* __restrict__ sm,
                          int* __restrict__ cbits128, int* __restrict__ sbits128, int* __restrict__ counts) {
    int p = blockIdx.x * TPB + threadIdx.x;   // 16384
    int y = p >> 7, x = p & 127;
    int src = (2 * y) * 256 + 2 * x;
    int cb = 0, sb = 0;
#pragma unroll
    for (int r = 0; r < 9; ++r) {
        cb |= (cm[r * 65536 + src] == 1) << r;
        sb |= (sm[r * 65536 + src] == 1) << r;
    }
    cbits128[p] = cb; sbits128[p] = sb;
    int lane = threadIdx.x & 63;
#pragma unroll
    for (int r = 0; r < 9; ++r) {
        unsigned long long b1 = __ballot((cb >> r) & 1);
        if (lane == 0) atomicAdd(&counts[32 + r], __popcll(b1));
        unsigned long long b2 = __ballot((sb >> r) & 1);
        if (lane == 0) atomicAdd(&counts[48 + r], __popcll(b2));
    }
}

// ---------------- stable per-region index compaction at 128x128 ----------------
__global__ void compact_k(const int* __restrict__ sbits128, const int* __restrict__ cbits128,
                          int* __restrict__ idxlist) {
    int r = blockIdx.x;        // 0..8
    int side = blockIdx.y;     // 0=style,1=content
    const int* bits = side ? cbits128 : sbits128;
    int* out = idxlist + (side * 9 + r) * 16384;
    __shared__ int lds[TPB];
    __shared__ int base_s;
    int t = threadIdx.x;
    if (t == 0) base_s = 0;
    __syncthreads();
    for (int chunk = 0; chunk < 64; ++chunk) {
        int pid = chunk * TPB + t;
        int flag = (bits[pid] >> r) & 1;
        lds[t] = flag;
        __syncthreads();
        for (int off = 1; off < TPB; off <<= 1) {
            int v = (t >= off) ? lds[t - off] : 0;
            __syncthreads();
            lds[t] += v;
            __syncthreads();
        }
        int pos = lds[t] - flag;
        int total = lds[TPB - 1];
        int base = base_s;
        if (flag) out[base + pos] = pid;
        __syncthreads();
        if (t == 0) base_s = base + total;
        __syncthreads();
    }
}

// ---------------- weight transpose: [oc][ick] -> [ick][oc] ----------------
__global__ void wtr_k(const float* __restrict__ w, float* __restrict__ wT, int OC, int ICK) {
    int i = blockIdx.x * TPB + threadIdx.x;
    int n = OC * ICK;
    if (i < n) {
        int oc = i / ICK;
        int t = i - oc * ICK;
        wT[t * OC + oc] = w[i];
    }
}

// ---------------- convs (direct, thread per output pixel, all oc in regs) ----------------
__global__ void conv1_k(const float* __restrict__ in, const float* __restrict__ wT,
                        const float* __restrict__ b, float* __restrict__ out) {
    int idx = blockIdx.x * TPB + threadIdx.x;   // 262144
    int ox = idx & 511, oy = idx >> 9;
    float acc[64];
#pragma unroll
    for (int oc = 0; oc < 64; ++oc) acc[oc] = b[oc];
    for (int ic = 0; ic < 3; ++ic)
        for (int ky = 0; ky < 3; ++ky) {
            int iy = 2 * oy - 1 + ky;
            if ((unsigned)iy < 1024u)
                for (int kx = 0; kx < 3; ++kx) {
                    int ix = 2 * ox - 1 + kx;
                    if ((unsigned)ix < 1024u) {
                        float v = in[ic * 1048576 + iy * 1024 + ix];
                        const float* wp = wT + (ic * 9 + ky * 3 + kx) * 64;
#pragma unroll
                        for (int oc = 0; oc < 64; ++oc) acc[oc] = fmaf(wp[oc], v, acc[oc]);
                    }
                }
        }
#pragma unroll
    for (int oc = 0; oc < 64; ++oc) out[oc * 262144 + idx] = fmaxf(acc[oc], 0.f);
}

__global__ void conv2_k(const float* __restrict__ in, const float* __restrict__ wT,
                        const float* __restrict__ b, float* __restrict__ out) {
    int idx = blockIdx.x * TPB + threadIdx.x;   // 65536
    int ox = idx & 255, oy = idx >> 8;
    float acc[32];
#pragma unroll
    for (int oc = 0; oc < 32; ++oc) acc[oc] = b[oc];
    for (int ic = 0; ic < 64; ++ic)
#pragma unroll
        for (int ky = 0; ky < 3; ++ky) {
            int iy = 2 * oy - 1 + ky;
            if ((unsigned)iy < 512u)
#pragma unroll
                for (int kx = 0; kx < 3; ++kx) {
                    int ix = 2 * ox - 1 + kx;
                    if ((unsigned)ix < 512u) {
                        float v = in[ic * 262144 + iy * 512 + ix];
                        const float* wp = wT + (ic * 9 + ky * 3 + kx) * 32;
#pragma unroll
                        for (int oc = 0; oc < 32; ++oc) acc[oc] = fmaf(wp[oc], v, acc[oc]);
                    }
                }
        }
#pragma unroll
    for (int oc = 0; oc < 32; ++oc) out[oc * 65536 + idx] = fmaxf(acc[oc], 0.f);
}

__global__ void conv3_k(const float* __restrict__ in, const float* __restrict__ wT,
                        const float* __restrict__ b, float* __restrict__ out) {
    int idx = blockIdx.x * TPB + threadIdx.x;   // 16384
    int ox = idx & 127, oy = idx >> 7;
    float acc[16];
#pragma unroll
    for (int oc = 0; oc < 16; ++oc) acc[oc] = b[oc];
    for (int ic = 0; ic < 32; ++ic)
#pragma unroll
        for (int ky = 0; ky < 3; ++ky) {
            int iy = 2 * oy - 1 + ky;
            if ((unsigned)iy < 256u)
#pragma unroll
                for (int kx = 0; kx < 3; ++kx) {
                    int ix = 2 * ox - 1 + kx;
                    if ((unsigned)ix < 256u) {
                        float v = in[ic * 65536 + iy * 256 + ix];
                        const float* wp = wT + (ic * 9 + ky * 3 + kx) * 16;
#pragma unroll
                        for (int oc = 0; oc < 16; ++oc) acc[oc] = fmaf(wp[oc], v, acc[oc]);
                    }
                }
        }
#pragma unroll
    for (int oc = 0; oc < 16; ++oc) out[oc * 16384 + idx] = acc[oc];   // no relu
}

// ---------------- adaptive max pool over compacted indices ----------------
__global__ void pool_k(const float* __restrict__ f3, const int* __restrict__ idxbase,
                       const int* __restrict__ cnt, float* __restrict__ pooled) {
    int r = blockIdx.x >> 4;   // 0..8
    int c = blockIdx.x & 15;   // 0..15
    int j = threadIdx.x;       // 0..255
    int n = cnt[r];
    float m = 0.f;
    if (n >= 1) {
        int start = (j * n) >> 8;
        int end = ((j + 1) * n + 255) >> 8;
        const int* il = idxbase + r * 16384;
        m = -__builtin_inff();
        for (int t = start; t < end; ++t) m = fmaxf(m, f3[c * 16384 + il[t]]);
    }
    pooled[(r * 16 + c) * 256 + j] = m;
}

// ---------------- FC: M[side][r][row] = fcw @ pooled + fcb (9 cols batched) ----------------
__global__ void fc_k(const float* __restrict__ fcw_s, const float* __restrict__ fcb_s,
                     const float* __restrict__ fcw_c, const float* __restrict__ fcb_c,
                     const float* __restrict__ pooled, float* __restrict__ Mout) {
    int row = blockIdx.x;                 // 0..4095
    int side = blockIdx.y;                // 0 style, 1 content
    const float* fcw = side ? fcw_c : fcw_s;
    const float* fcb = side ? fcb_c : fcb_s;
    const float* P = pooled + side * 9 * 4096;
    int t = threadIdx.x;
    float acc[9];
#pragma unroll
    for (int r = 0; r < 9; ++r) acc[r] = 0.f;
    for (int k = t; k < 4096; k += TPB) {
        float w = fcw[row * 4096 + k];
#pragma unroll
        for (int r = 0; r < 9; ++r) acc[r] = fmaf(w, P[r * 4096 + k], acc[r]);
    }
    __shared__ float red[9 * TPB];
#pragma unroll
    for (int r = 0; r < 9; ++r) red[r * TPB + t] = acc[r];
    __syncthreads();
    for (int off = TPB / 2; off > 0; off >>= 1) {
        if (t < off)
#pragma unroll
            for (int r = 0; r < 9; ++r) red[r * TPB + t] += red[r * TPB + t + off];
        __syncthreads();
    }
    if (t < 9) Mout[(side * 9 + t) * 4096 + row] = red[t * TPB] + fcb[row];
}

// ---------------- per-region style mean sums (one block per channel) ----------------
__global__ void smean_k(const float* __restrict__ sF, const int* __restrict__ sbits,
                        float* __restrict__ ssum) {
    int c = blockIdx.x;   // 0..255
    int t = threadIdx.x;
    float acc[9];
#pragma unroll
    for (int r = 0; r < 9; ++r) acc[r] = 0.f;
    for (int p = t; p < 65536; p += TPB) {
        float v = sF[c * 65536 + p];
        int b = sbits[p];
#pragma unroll
        for (int r = 0; r < 9; ++r)
            if (b & (1 << r)) acc[r] += v;
    }
    __shared__ float red[9 * TPB];
#pragma unroll
    for (int r = 0; r < 9; ++r) red[r * TPB + t] = acc[r];
    __syncthreads();
    for (int off = TPB / 2; off > 0; off >>= 1) {
        if (t < off)
#pragma unroll
            for (int r = 0; r < 9; ++r) red[r * TPB + t] += red[r * TPB + t + off];
        __syncthreads();
    }
    if (t < 9) ssum[t * 256 + c] = red[t * TPB];
}

// ---------------- Xc = compress_w @ cF (bias dropped: cancels under centering) ----------------
__global__ void xgemm_k(const float* __restrict__ cF, const float* __restrict__ cw,
                        float* __restrict__ Xc) {
    int p = blockIdx.x * TPB + threadIdx.x;   // 65536
    float acc[64];
#pragma unroll
    for (int m = 0; m < 64; ++m) acc[m] = 0.f;
#pragma unroll 4
    for (int k = 0; k < 256; ++k) {
        float v = cF[k * 65536 + p];
#pragma unroll
        for (int m = 0; m < 64; ++m) acc[m] = fmaf(cw[m * 256 + k], v, acc[m]);
    }
#pragma unroll
    for (int m = 0; m < 64; ++m) Xc[m * 65536 + p] = acc[m];
}

__global__ void mu_k(const float* __restrict__ Xc, float* __restrict__ mu) {
    int m = blockIdx.x;   // 0..63
    int t = threadIdx.x;
    float a = 0.f;
    for (int p = t; p < 65536; p += TPB) a += Xc[m * 65536 + p];
    __shared__ float red[TPB];
    red[t] = a;
    __syncthreads();
    for (int off = TPB / 2; off > 0; off >>= 1) {
        if (t < off) red[t] += red[t + off];
        __syncthreads();
    }
    if (t == 0) mu[m] = red[0] * (1.f / 65536.f);
}

// ---------------- T[r] = sM[r] @ cM[r]; slot 9 = identity ----------------
__global__ void tmat_k(const float* __restrict__ M, float* __restrict__ T) {
    int r = blockIdx.x;   // 0..9
    if (r == 9) {
        for (int e = threadIdx.x; e < 4096; e += TPB)
            T[9 * 4096 + e] = ((e >> 6) == (e & 63)) ? 1.f : 0.f;
        return;
    }
    __shared__ float sS[4096], sC[4096];
    for (int e = threadIdx.x; e < 4096; e += TPB) {
        sS[e] = M[(0 * 9 + r) * 4096 + e];
        sC[e] = M[(1 * 9 + r) * 4096 + e];
    }
    __syncthreads();
    for (int e = threadIdx.x; e < 4096; e += TPB) {
        int m = e >> 6, n = e & 63;
        float a = 0.f;
#pragma unroll 8
        for (int k = 0; k < 64; ++k) a = fmaf(sS[m * 64 + k], sC[k * 64 + n], a);
        T[r * 4096 + e] = a;
    }
}

// ---------------- active flags + per-region style means ----------------
__global__ void finalize_k(const int* __restrict__ counts, int* __restrict__ activemask,
                           const float* __restrict__ ssum, float* __restrict__ sMeanArr) {
    __shared__ int am;
    if (threadIdx.x == 0) am = 0;
    __syncthreads();
    if (threadIdx.x < 9) {
        int r = threadIdx.x;
        if (counts[0 + r] >= 10 && counts[16 + r] >= 10 && counts[32 + r] >= 10 && counts[48 + r] >= 10)
            atomicOr(&am, 1 << r);
    }
    __syncthreads();
    if (threadIdx.x == 0) *activemask = am;
    for (int e = threadIdx.x; e < 2560; e += TPB) {
        int r = e >> 8, c = e & 255;
        float v = 0.f;
        if (r < 9 && ((am >> r) & 1)) v = ssum[r * 256 + c] / (float)counts[16 + r];
        sMeanArr[e] = v;
    }
}

// ---------------- stage 1: trans_p = T[r(p)] @ (Xc_p - mu) ----------------
__global__ void stage1_k(const float* __restrict__ Xc, const float* __restrict__ mu,
                         const float* __restrict__ T, const int* __restrict__ cbits,
                         const int* __restrict__ activemask, int* __restrict__ rmap,
                         float* __restrict__ trans) {
    int p = blockIdx.x * TPB + threadIdx.x;   // 65536
    int am = *activemask;
    int bits = cbits[p] & am;
    int r = bits ? (31 - __clz(bits)) : 9;
    rmap[p] = r;
    const float* Tr = T + r * 4096;
    float acc[64];
#pragma unroll
    for (int m = 0; m < 64; ++m) acc[m] = 0.f;
    for (int k0 = 0; k0 < 64; k0 += 4) {
        float xv0 = Xc[(k0 + 0) * 65536 + p] - mu[k0 + 0];
        float xv1 = Xc[(k0 + 1) * 65536 + p] - mu[k0 + 1];
        float xv2 = Xc[(k0 + 2) * 65536 + p] - mu[k0 + 2];
        float xv3 = Xc[(k0 + 3) * 65536 + p] - mu[k0 + 3];
#pragma unroll
        for (int m = 0; m < 64; ++m) {
            float4 t4 = *(const float4*)(Tr + m * 64 + k0);
            acc[m] = fmaf(t4.x, xv0, acc[m]);
            acc[m] = fmaf(t4.y, xv1, acc[m]);
            acc[m] = fmaf(t4.z, xv2, acc[m]);
            acc[m] = fmaf(t4.w, xv3, acc[m]);
        }
    }
#pragma unroll
    for (int m = 0; m < 64; ++m) trans[m * 65536 + p] = acc[m];
}

// ---------------- stage 2: out = unzip_w @ trans + unzip_b + sMean[r(p)] ----------------
__global__ void stage2_k(const float* __restrict__ trans, const float* __restrict__ uz,
                         const float* __restrict__ uzb, const float* __restrict__ sMeanArr,
                         const int* __restrict__ rmap, float* __restrict__ out) {
    int p = blockIdx.x * TPB + threadIdx.x;   // 65536
    int g = blockIdx.y;                        // 0..3 (64 out channels each)
    int r = rmap[p];
    float acc[64];
#pragma unroll
    for (int m = 0; m < 64; ++m) acc[m] = uzb[g * 64 + m] + sMeanArr[r * 256 + g * 64 + m];
#pragma unroll 4
    for (int k = 0; k < 64; ++k) {
        float tv = trans[k * 65536 + p];
#pragma unroll
        for (int m = 0; m < 64; ++m) acc[m] = fmaf(uz[(g * 64 + m) * 64 + k], tv, acc[m]);
    }
#pragma unroll
    for (int m = 0; m < 64; ++m) out[(g * 64 + m) * 65536 + p] = acc[m];
}

// ---------------- launch ----------------
extern "C" void kernel_launch(void* const* d_in, const int* in_sizes, int n_in,
                              void* d_out, int out_size, void* d_ws, size_t ws_size,
                              hipStream_t stream) {
    const float* cF         = (const float*)d_in[0];
    const float* sF         = (const float*)d_in[1];
    const float* content    = (const float*)d_in[2];
    const float* style      = (const float*)d_in[3];
    const int*   cmasks     = (const int*)d_in[4];
    const int*   smasks     = (const int*)d_in[5];
    const float* compress_w = (const float*)d_in[6];
    const float* unzip_w    = (const float*)d_in[8];
    const float* unzip_b    = (const float*)d_in[9];
    const float* s_w1 = (const float*)d_in[10]; const float* s_b1 = (const float*)d_in[11];
    const float* s_w2 = (const float*)d_in[12]; const float* s_b2 = (const float*)d_in[13];
    const float* s_w3 = (const float*)d_in[14]; const float* s_b3 = (const float*)d_in[15];
    const float* s_fcw = (const float*)d_in[16]; const float* s_fcb = (const float*)d_in[17];
    const float* c_w1 = (const float*)d_in[18]; const float* c_b1 = (const float*)d_in[19];
    const float* c_w2 = (const float*)d_in[20]; const float* c_b2 = (const float*)d_in[21];
    const float* c_w3 = (const float*)d_in[22]; const float* c_b3 = (const float*)d_in[23];
    const float* c_fcw = (const float*)d_in[24]; const float* c_fcb = (const float*)d_in[25];
    float* out = (float*)d_out;
    char* ws = (char*)d_ws;
#define WF(o) ((float*)(ws + (o)))
#define WI(o) ((int*)(ws + (o)))

    init_k<<<8, TPB, 0, stream>>>(WI(0), (int)(0x5000 / 4));
    bits_k<<<256, TPB, 0, stream>>>(cmasks, smasks, WI(OFF_CBITS), WI(OFF_SBITS), WI(OFF_COUNTS));
    bits128_k<<<64, TPB, 0, stream>>>(cmasks, smasks, WI(OFF_CBITS128), WI(OFF_SBITS128), WI(OFF_COUNTS));
    compact_k<<<dim3(9, 2), TPB, 0, stream>>>(WI(OFF_SBITS128), WI(OFF_CBITS128), WI(OFF_IDX));

    // independent heavy GEMM path
    xgemm_k<<<256, TPB, 0, stream>>>(cF, compress_w, WF(OFF_XC));
    mu_k<<<64, TPB, 0, stream>>>(WF(OFF_XC), WF(OFF_MU));
    smean_k<<<256, TPB, 0, stream>>>(sF, WI(OFF_SBITS), WF(OFF_SSUM));

    // style CNN
    wtr_k<<<7, TPB, 0, stream>>>(s_w1, WF(OFF_W1T), 64, 27);
    wtr_k<<<72, TPB, 0, stream>>>(s_w2, WF(OFF_W2T), 32, 576);
    wtr_k<<<18, TPB, 0, stream>>>(s_w3, WF(OFF_W3T), 16, 288);
    conv1_k<<<1024, TPB, 0, stream>>>(style, WF(OFF_W1T), s_b1, WF(OFF_F1));
    conv2_k<<<256, TPB, 0, stream>>>(WF(OFF_F1), WF(OFF_W2T), s_b2, WF(OFF_F2));
    conv3_k<<<64, TPB, 0, stream>>>(WF(OFF_F2), WF(OFF_W3T), s_b3, WF(OFF_F3));
    pool_k<<<144, TPB, 0, stream>>>(WF(OFF_F3), WI(OFF_IDX), WI(OFF_COUNTS) + 48, WF(OFF_POOLED));

    // content CNN
    wtr_k<<<7, TPB, 0, stream>>>(c_w1, WF(OFF_W1T), 64, 27);
    wtr_k<<<72, TPB, 0, stream>>>(c_w2, WF(OFF_W2T), 32, 576);
    wtr_k<<<18, TPB, 0, stream>>>(c_w3, WF(OFF_W3T), 16, 288);
    conv1_k<<<1024, TPB, 0, stream>>>(content, WF(OFF_W1T), c_b1, WF(OFF_F1));
    conv2_k<<<256, TPB, 0, stream>>>(WF(OFF_F1), WF(OFF_W2T), c_b2, WF(OFF_F2));
    conv3_k<<<64, TPB, 0, stream>>>(WF(OFF_F2), WF(OFF_W3T), c_b3, WF(OFF_F3));
    pool_k<<<144, TPB, 0, stream>>>(WF(OFF_F3), WI(OFF_IDX) + 9 * 16384, WI(OFF_COUNTS) + 32,
                                    WF(OFF_POOLED) + 9 * 4096);

    fc_k<<<dim3(4096, 2), TPB, 0, stream>>>(s_fcw, s_fcb, c_fcw, c_fcb, WF(OFF_POOLED), WF(OFF_M));
    tmat_k<<<10, TPB, 0, stream>>>(WF(OFF_M), WF(OFF_T));
    finalize_k<<<1, TPB, 0, stream>>>(WI(OFF_COUNTS), WI(OFF_ACTIVE), WF(OFF_SSUM), WF(OFF_SMEAN));

    stage1_k<<<256, TPB, 0, stream>>>(WF(OFF_XC), WF(OFF_MU), WF(OFF_T), WI(OFF_CBITS),
                                      WI(OFF_ACTIVE), WI(OFF_RMAP), WF(OFF_TRANS));
    stage2_k<<<dim3(256, 4), TPB, 0, stream>>>(WF(OFF_TRANS), unzip_w, unzip_b, WF(OFF_SMEAN),
                                               WI(OFF_RMAP), out);
}

// Round 2
// 1220.433 us; speedup vs baseline: 1.3364x; 1.3364x over previous
//
#include <hip/hip_runtime.h>
#include <math.h>

#define TPB 256

// ---------------- workspace layout (bytes) ----------------
constexpr size_t OFF_COUNTS   = 0x000000; // 64 ints
constexpr size_t OFF_ACTIVE   = 0x000100; // 1 int
constexpr size_t OFF_LCNT     = 0x000140; // 10 ints
constexpr size_t OFF_MUSUM    = 0x000200; // 64 floats
constexpr size_t OFF_MU       = 0x000400; // 64 floats
constexpr size_t OFF_SSUM     = 0x000800; // float [4][9][256] partials
constexpr size_t OFF_SMEAN    = 0x00A000; // float [10][256]
constexpr size_t OFF_W1T      = 0x00D000; // [27][64]
constexpr size_t OFF_W3T      = 0x00F000; // [288][16]
constexpr size_t OFF_W2T      = 0x014000; // [576][32]
constexpr size_t OFF_CWT      = 0x028000; // [256][64]  compress_w^T
constexpr size_t OFF_POOLED   = 0x040000; // float [2][9][4096]
constexpr size_t OFF_M        = 0x090000; // float [2][9][4096]
constexpr size_t OFF_P        = 0x0E0000; // float [9][256][64]
constexpr size_t OFF_U        = 0x180000; // float [10][256][64]
constexpr size_t OFF_V        = 0x228000; // float [10][256]
constexpr size_t OFF_CBITS    = 0x230000; // int[65536]
constexpr size_t OFF_SBITS    = 0x270000; // int[65536]
constexpr size_t OFF_CBITS128 = 0x2B0000; // int[16384]
constexpr size_t OFF_SBITS128 = 0x2C0000; // int[16384]
constexpr size_t OFF_IDX      = 0x2D0000; // int [2][9][16384]
constexpr size_t OFF_RLIST    = 0x400000; // int [10][65536]
constexpr size_t OFF_XCT      = 0x700000; // float [65536][64]  Xc^T
constexpr size_t OFF_F1       = 0x1700000; // float [64][512][512]
constexpr size_t OFF_F2       = 0x5700000; // float [32][256][256]
constexpr size_t OFF_F3       = 0x5F00000; // float [16][128][128]
// total 0x6000000 = 96 MiB

__global__ void init_k(int* p, int n) {
    for (int i = blockIdx.x * TPB + threadIdx.x; i < n; i += gridDim.x * TPB) p[i] = 0;
}

// ---------------- mask bit planes + counts ----------------
__global__ void bits_k(const int* __restrict__ cm, const int* __restrict__ sm,
                       int* __restrict__ cbits, int* __restrict__ sbits, int* __restrict__ counts) {
    int p = blockIdx.x * TPB + threadIdx.x;
    int cb = 0, sb = 0;
#pragma unroll
    for (int r = 0; r < 9; ++r) {
        cb |= (cm[r * 65536 + p] == 1) << r;
        sb |= (sm[r * 65536 + p] == 1) << r;
    }
    cbits[p] = cb; sbits[p] = sb;
    int lane = threadIdx.x & 63;
#pragma unroll
    for (int r = 0; r < 9; ++r) {
        unsigned long long b1 = __ballot((cb >> r) & 1);
        if (lane == 0) atomicAdd(&counts[0 + r], __popcll(b1));
        unsigned long long b2 = __ballot((sb >> r) & 1);
        if (lane == 0) atomicAdd(&counts[16 + r], __popcll(b2));
    }
}

__global__ void bits128_k(const int* __restrict__ cm, const int* __restrict__ sm,
                          int* __restrict__ cbits128, int* __restrict__ sbits128, int* __restrict__ counts) {
    int p = blockIdx.x * TPB + threadIdx.x;
    int y = p >> 7, x = p & 127;
    int src = (2 * y) * 256 + 2 * x;
    int cb = 0, sb = 0;
#pragma unroll
    for (int r = 0; r < 9; ++r) {
        cb |= (cm[r * 65536 + src] == 1) << r;
        sb |= (sm[r * 65536 + src] == 1) << r;
    }
    cbits128[p] = cb; sbits128[p] = sb;
    int lane = threadIdx.x & 63;
#pragma unroll
    for (int r = 0; r < 9; ++r) {
        unsigned long long b1 = __ballot((cb >> r) & 1);
        if (lane == 0) atomicAdd(&counts[32 + r], __popcll(b1));
        unsigned long long b2 = __ballot((sb >> r) & 1);
        if (lane == 0) atomicAdd(&counts[48 + r], __popcll(b2));
    }
}

// ---------------- stable (ordered) compaction at 128x128 for pooling ----------------
__global__ void compact_k(const int* __restrict__ sbits128, const int* __restrict__ cbits128,
                          int* __restrict__ idxlist) {
    int r = blockIdx.x, side = blockIdx.y;
    const int* bits = side ? cbits128 : sbits128;
    int* out = idxlist + (side * 9 + r) * 16384;
    __shared__ int lds[TPB];
    __shared__ int base_s;
    int t = threadIdx.x;
    if (t == 0) base_s = 0;
    __syncthreads();
    for (int chunk = 0; chunk < 64; ++chunk) {
        int pid = chunk * TPB + t;
        int flag = (bits[pid] >> r) & 1;
        lds[t] = flag;
        __syncthreads();
        for (int off = 1; off < TPB; off <<= 1) {
            int v = (t >= off) ? lds[t - off] : 0;
            __syncthreads();
            lds[t] += v;
            __syncthreads();
        }
        int pos = lds[t] - flag;
        int total = lds[TPB - 1];
        int base = base_s;
        if (flag) out[base + pos] = pid;
        __syncthreads();
        if (t == 0) base_s = base + total;
        __syncthreads();
    }
}

// ---------------- weight transpose [oc][ick] -> [ick][oc] ----------------
__global__ void wtr_k(const float* __restrict__ w, float* __restrict__ wT, int OC, int ICK) {
    int i = blockIdx.x * TPB + threadIdx.x;
    int n = OC * ICK;
    if (i < n) {
        int oc = i / ICK;
        int t = i - oc * ICK;
        wT[t * OC + oc] = w[i];
    }
}

// ---------------- per-region style mean partial sums ----------------
__global__ void smean_k(const float* __restrict__ sF, const int* __restrict__ sbits,
                        float* __restrict__ ssump) {
    int c = blockIdx.x;       // channel
    int pg = blockIdx.y;      // pixel quarter
    int t = threadIdx.x;
    float acc[9];
#pragma unroll
    for (int r = 0; r < 9; ++r) acc[r] = 0.f;
    int p0 = pg * 16384;
    for (int p = p0 + t; p < p0 + 16384; p += TPB) {
        float v = sF[c * 65536 + p];
        int b = sbits[p];
#pragma unroll
        for (int r = 0; r < 9; ++r)
            if (b & (1 << r)) acc[r] += v;
    }
    __shared__ float red[9 * TPB];
#pragma unroll
    for (int r = 0; r < 9; ++r) red[r * TPB + t] = acc[r];
    __syncthreads();
    for (int off = TPB / 2; off > 0; off >>= 1) {
        if (t < off)
#pragma unroll
            for (int r = 0; r < 9; ++r) red[r * TPB + t] += red[r * TPB + t + off];
        __syncthreads();
    }
    if (t < 9) ssump[(pg * 9 + t) * 256 + c] = red[t * TPB];
}

// ---------------- active mask + per-region style means ----------------
__global__ void finalize_k(const int* __restrict__ counts, int* __restrict__ activemask,
                           const float* __restrict__ ssump, float* __restrict__ sMeanArr) {
    __shared__ int am;
    if (threadIdx.x == 0) am = 0;
    __syncthreads();
    if (threadIdx.x < 9) {
        int r = threadIdx.x;
        if (counts[0 + r] >= 10 && counts[16 + r] >= 10 && counts[32 + r] >= 10 && counts[48 + r] >= 10)
            atomicOr(&am, 1 << r);
    }
    __syncthreads();
    if (threadIdx.x == 0) *activemask = am;
    for (int e = threadIdx.x; e < 2560; e += TPB) {
        int r = e >> 8, c = e & 255;
        float v = 0.f;
        if (r < 9 && ((am >> r) & 1)) {
            float s = ssump[(0 * 9 + r) * 256 + c] + ssump[(1 * 9 + r) * 256 + c]
                    + ssump[(2 * 9 + r) * 256 + c] + ssump[(3 * 9 + r) * 256 + c];
            v = s / (float)counts[16 + r];
        }
        sMeanArr[e] = v;
    }
}

// ---------------- region pixel lists at 256-res (order-free, ballot-aggregated) --------
__global__ void rlist_k(const int* __restrict__ cbits, const int* __restrict__ activemask,
                        int* __restrict__ lcnt, int* __restrict__ rlist) {
    int p = blockIdx.x * TPB + threadIdx.x;
    int am = *activemask;
    int bits = cbits[p] & am;
    int r = bits ? (31 - __clz(bits)) : 9;
    int lane = threadIdx.x & 63;
#pragma unroll
    for (int rr = 0; rr < 10; ++rr) {
        unsigned long long m = __ballot(r == rr);
        if (m) {
            int leader = __ffsll((unsigned long long)m) - 1;
            int base = 0;
            if (lane == leader) base = atomicAdd(&lcnt[rr], __popcll(m));
            base = __shfl(base, leader);
            if (r == rr) {
                int prefix = __popcll(m & ((1ull << lane) - 1ull));
                rlist[rr * 65536 + base + prefix] = p;
            }
        }
    }
}

// ---------------- conv1: 1024x1024x3 -> 512x512x64, oc-split 2 ----------------
__global__ void conv1_k(const float* __restrict__ in, const float* __restrict__ wT,
                        const float* __restrict__ b, float* __restrict__ out) {
    int idx = blockIdx.x * TPB + threadIdx.x;   // 262144
    int og = blockIdx.y;                         // 0..1
    int ox = idx & 511, oy = idx >> 9;
    float acc[32];
#pragma unroll
    for (int oc = 0; oc < 32; ++oc) acc[oc] = b[og * 32 + oc];
    for (int ic = 0; ic < 3; ++ic)
#pragma unroll
        for (int ky = 0; ky < 3; ++ky) {
            int iy = 2 * oy - 1 + ky;
            if ((unsigned)iy < 1024u)
#pragma unroll
                for (int kx = 0; kx < 3; ++kx) {
                    int ix = 2 * ox - 1 + kx;
                    if ((unsigned)ix < 1024u) {
                        float v = in[ic * 1048576 + iy * 1024 + ix];
                        const float4* wp = (const float4*)(wT + (ic * 9 + ky * 3 + kx) * 64 + og * 32);
#pragma unroll
                        for (int q = 0; q < 8; ++q) {
                            float4 w4 = wp[q];
                            acc[q * 4 + 0] = fmaf(w4.x, v, acc[q * 4 + 0]);
                            acc[q * 4 + 1] = fmaf(w4.y, v, acc[q * 4 + 1]);
                            acc[q * 4 + 2] = fmaf(w4.z, v, acc[q * 4 + 2]);
                            acc[q * 4 + 3] = fmaf(w4.w, v, acc[q * 4 + 3]);
                        }
                    }
                }
        }
#pragma unroll
    for (int oc = 0; oc < 32; ++oc) out[(og * 32 + oc) * 262144 + idx] = fmaxf(acc[oc], 0.f);
}

// ---------------- conv2: bias init, ic-split-4 atomic partials, relu ----------------
__global__ void f2init_k(const float* __restrict__ b, float* __restrict__ F2) {
    int idx = blockIdx.x * TPB + threadIdx.x;   // 65536
#pragma unroll
    for (int oc = 0; oc < 32; ++oc) F2[oc * 65536 + idx] = b[oc];
}

__global__ void conv2p_k(const float* __restrict__ in, const float* __restrict__ wT,
                         float* __restrict__ F2) {
    int idx = blockIdx.x * TPB + threadIdx.x;   // 65536
    int icg = blockIdx.y;                        // 0..3 (16 ic each)
    int ox = idx & 255, oy = idx >> 8;
    float acc[32];
#pragma unroll
    for (int oc = 0; oc < 32; ++oc) acc[oc] = 0.f;
    for (int ic = icg * 16; ic < icg * 16 + 16; ++ic) {
        const float* base = in + ic * 262144;
#pragma unroll
        for (int ky = 0; ky < 3; ++ky) {
            int iy = 2 * oy - 1 + ky;
            if ((unsigned)iy < 512u)
#pragma unroll
                for (int kx = 0; kx < 3; ++kx) {
                    int ix = 2 * ox - 1 + kx;
                    if ((unsigned)ix < 512u) {
                        float v = base[iy * 512 + ix];
                        const float4* wp = (const float4*)(wT + (ic * 9 + ky * 3 + kx) * 32);
#pragma unroll
                        for (int q = 0; q < 8; ++q) {
                            float4 w4 = wp[q];
                            acc[q * 4 + 0] = fmaf(w4.x, v, acc[q * 4 + 0]);
                            acc[q * 4 + 1] = fmaf(w4.y, v, acc[q * 4 + 1]);
                            acc[q * 4 + 2] = fmaf(w4.z, v, acc[q * 4 + 2]);
                            acc[q * 4 + 3] = fmaf(w4.w, v, acc[q * 4 + 3]);
                        }
                    }
                }
        }
    }
#pragma unroll
    for (int oc = 0; oc < 32; ++oc) atomicAdd(&F2[oc * 65536 + idx], acc[oc]);
}

__global__ void relu2_k(float* __restrict__ F2) {
    int i = blockIdx.x * TPB + threadIdx.x;   // 524288 float4s
    float4* p = (float4*)F2;
    float4 v = p[i];
    v.x = fmaxf(v.x, 0.f); v.y = fmaxf(v.y, 0.f);
    v.z = fmaxf(v.z, 0.f); v.w = fmaxf(v.w, 0.f);
    p[i] = v;
}

// ---------------- conv3: bias init + ic-split-4 atomic partials (no relu) ------------
__global__ void f3init_k(const float* __restrict__ b, float* __restrict__ F3) {
    int idx = blockIdx.x * TPB + threadIdx.x;   // 16384
#pragma unroll
    for (int oc = 0; oc < 16; ++oc) F3[oc * 16384 + idx] = b[oc];
}

__global__ void conv3p_k(const float* __restrict__ in, const float* __restrict__ wT,
                         float* __restrict__ F3) {
    int idx = blockIdx.x * TPB + threadIdx.x;   // 16384
    int icg = blockIdx.y;                        // 0..3 (8 ic each)
    int ox = idx & 127, oy = idx >> 7;
    float acc[16];
#pragma unroll
    for (int oc = 0; oc < 16; ++oc) acc[oc] = 0.f;
    for (int ic = icg * 8; ic < icg * 8 + 8; ++ic) {
        const float* base = in + ic * 65536;
#pragma unroll
        for (int ky = 0; ky < 3; ++ky) {
            int iy = 2 * oy - 1 + ky;
            if ((unsigned)iy < 256u)
#pragma unroll
                for (int kx = 0; kx < 3; ++kx) {
                    int ix = 2 * ox - 1 + kx;
                    if ((unsigned)ix < 256u) {
                        float v = base[iy * 256 + ix];
                        const float4* wp = (const float4*)(wT + (ic * 9 + ky * 3 + kx) * 16);
#pragma unroll
                        for (int q = 0; q < 4; ++q) {
                            float4 w4 = wp[q];
                            acc[q * 4 + 0] = fmaf(w4.x, v, acc[q * 4 + 0]);
                            acc[q * 4 + 1] = fmaf(w4.y, v, acc[q * 4 + 1]);
                            acc[q * 4 + 2] = fmaf(w4.z, v, acc[q * 4 + 2]);
                            acc[q * 4 + 3] = fmaf(w4.w, v, acc[q * 4 + 3]);
                        }
                    }
                }
        }
    }
#pragma unroll
    for (int oc = 0; oc < 16; ++oc) atomicAdd(&F3[oc * 16384 + idx], acc[oc]);
}

// ---------------- adaptive max pool over ordered compacted indices ----------------
__global__ void pool_k(const float* __restrict__ f3, const int* __restrict__ idxbase,
                       const int* __restrict__ cnt, float* __restrict__ pooled) {
    int r = blockIdx.x >> 4;
    int c = blockIdx.x & 15;
    int j = threadIdx.x;
    int n = cnt[r];
    float m = 0.f;
    if (n >= 1) {
        int start = (j * n) >> 8;
        int end = ((j + 1) * n + 255) >> 8;
        const int* il = idxbase + r * 16384;
        m = -__builtin_inff();
        for (int t = start; t < end; ++t) m = fmaxf(m, f3[c * 16384 + il[t]]);
    }
    pooled[(r * 16 + c) * 256 + j] = m;
}

// ---------------- FC: M[side][r][row] (9 cols batched per row-block) ----------------
__global__ void fc_k(const float* __restrict__ fcw_s, const float* __restrict__ fcb_s,
                     const float* __restrict__ fcw_c, const float* __restrict__ fcb_c,
                     const float* __restrict__ pooled, float* __restrict__ Mout) {
    int row = blockIdx.x;
    int side = blockIdx.y;
    const float* fcw = side ? fcw_c : fcw_s;
    const float* fcb = side ? fcb_c : fcb_s;
    const float* P = pooled + side * 9 * 4096;
    int t = threadIdx.x;
    float acc[9];
#pragma unroll
    for (int r = 0; r < 9; ++r) acc[r] = 0.f;
    for (int k = t; k < 4096; k += TPB) {
        float w = fcw[row * 4096 + k];
#pragma unroll
        for (int r = 0; r < 9; ++r) acc[r] = fmaf(w, P[r * 4096 + k], acc[r]);
    }
    __shared__ float red[9 * TPB];
#pragma unroll
    for (int r = 0; r < 9; ++r) red[r * TPB + t] = acc[r];
    __syncthreads();
    for (int off = TPB / 2; off > 0; off >>= 1) {
        if (t < off)
#pragma unroll
            for (int r = 0; r < 9; ++r) red[r * TPB + t] += red[r * TPB + t + off];
        __syncthreads();
    }
    if (t < 9) Mout[(side * 9 + t) * 4096 + row] = red[t * TPB] + fcb[row];
}

// ---------------- Xc^T = (compress_w @ cF)^T, m-split 4, f4 uniform weights ---------
__global__ void xgemm_k(const float* __restrict__ cF, const float* __restrict__ cwT,
                        float* __restrict__ XcT) {
    int p = blockIdx.x * TPB + threadIdx.x;   // 65536
    int m0 = blockIdx.y * 16;
    float acc[16];
#pragma unroll
    for (int m = 0; m < 16; ++m) acc[m] = 0.f;
    for (int k0 = 0; k0 < 256; k0 += 4) {
        float xv[4];
#pragma unroll
        for (int i = 0; i < 4; ++i) xv[i] = cF[(k0 + i) * 65536 + p];
#pragma unroll
        for (int i = 0; i < 4; ++i) {
            const float4* wp = (const float4*)(cwT + (k0 + i) * 64 + m0);
#pragma unroll
            for (int q = 0; q < 4; ++q) {
                float4 w4 = wp[q];
                acc[q * 4 + 0] = fmaf(w4.x, xv[i], acc[q * 4 + 0]);
                acc[q * 4 + 1] = fmaf(w4.y, xv[i], acc[q * 4 + 1]);
                acc[q * 4 + 2] = fmaf(w4.z, xv[i], acc[q * 4 + 2]);
                acc[q * 4 + 3] = fmaf(w4.w, xv[i], acc[q * 4 + 3]);
            }
        }
    }
    float4* op = (float4*)(XcT + p * 64 + m0);
#pragma unroll
    for (int q = 0; q < 4; ++q)
        op[q] = make_float4(acc[q * 4 + 0], acc[q * 4 + 1], acc[q * 4 + 2], acc[q * 4 + 3]);
}

// ---------------- mu from Xc^T ----------------
__global__ void muacc_k(const float* __restrict__ XcT, float* __restrict__ musum) {
    int t = threadIdx.x;
    int m = t & 63, sub = t >> 6;
    int p0 = blockIdx.x * 256;
    float a = 0.f;
    for (int i = 0; i < 64; ++i) a += XcT[(p0 + sub + i * 4) * 64 + m];
    __shared__ float red[TPB];
    red[t] = a;
    __syncthreads();
    if (t < 64) atomicAdd(&musum[t], red[t] + red[t + 64] + red[t + 128] + red[t + 192]);
}

__global__ void mufin_k(const float* __restrict__ musum, float* __restrict__ mu) {
    int t = threadIdx.x;
    if (t < 64) mu[t] = musum[t] * (1.f / 65536.f);
}

// ---------------- U/V precompute:  P_r = uw @ sM_r ;  U_r = P_r @ cM_r --------------
__global__ void uprep1_k(const float* __restrict__ uw, const float* __restrict__ M,
                         float* __restrict__ P) {
    int idx = blockIdx.x * TPB + threadIdx.x;   // 9*256*64 = 147456
    int r = idx / 16384;
    int rem = idx & 16383;
    int c = rem >> 6, k = rem & 63;
    float a = 0.f;
#pragma unroll 8
    for (int i = 0; i < 64; ++i) a = fmaf(uw[c * 64 + i], M[r * 4096 + i * 64 + k], a);
    P[idx] = a;
}

__global__ void uprep2_k(const float* __restrict__ uw, const float* __restrict__ M,
                         const float* __restrict__ P, float* __restrict__ U) {
    int idx = blockIdx.x * TPB + threadIdx.x;   // 10*256*64 = 163840
    int r = idx / 16384;
    int rem = idx & 16383;
    int c = rem >> 6, j = rem & 63;
    if (r == 9) { U[idx] = uw[c * 64 + j]; return; }
    float a = 0.f;
#pragma unroll 8
    for (int k = 0; k < 64; ++k) a = fmaf(P[r * 16384 + c * 64 + k], M[(9 + r) * 4096 + k * 64 + j], a);
    U[idx] = a;
}

__global__ void uprep3_k(const float* __restrict__ U, const float* __restrict__ mu,
                         const float* __restrict__ uzb, const float* __restrict__ sMeanArr,
                         float* __restrict__ V) {
    int r = blockIdx.x;       // 0..9
    int c = threadIdx.x;      // 0..255
    float a = uzb[c] + sMeanArr[r * 256 + c];
#pragma unroll 8
    for (int j = 0; j < 64; ++j) a -= U[r * 16384 + c * 64 + j] * mu[j];
    V[r * 256 + c] = a;
}

// ---------------- out[:,p] = U_r @ Xc_p + V_r  (region-compacted blocks) -------------
__global__ void ustage_k(const float* __restrict__ XcT, const float* __restrict__ U,
                         const float* __restrict__ V, const int* __restrict__ lcnt,
                         const int* __restrict__ rlist, float* __restrict__ out) {
    int r = blockIdx.x >> 8;
    int chunk = blockIdx.x & 255;
    int ocg = blockIdx.y;     // 0..3 (64 oc each)
    int n = lcnt[r];
    int start = chunk * 256;
    if (start >= n) return;
    int i = start + threadIdx.x;
    bool valid = i < n;
    int pix = rlist[r * 65536 + (valid ? i : n - 1)];
    float4 xv[16];
    const float4* xp = (const float4*)(XcT + pix * 64);
#pragma unroll
    for (int q = 0; q < 16; ++q) xv[q] = xp[q];
    const float* Ur = U + r * 16384 + ocg * 64 * 64;
    const float* Vr = V + r * 256 + ocg * 64;
    float acc[64];
#pragma unroll
    for (int oc = 0; oc < 64; ++oc) {
        float a = Vr[oc];
        const float4* up = (const float4*)(Ur + oc * 64);
#pragma unroll
        for (int q = 0; q < 16; ++q) {
            float4 u4 = up[q];
            a = fmaf(u4.x, xv[q].x, a);
            a = fmaf(u4.y, xv[q].y, a);
            a = fmaf(u4.z, xv[q].z, a);
            a = fmaf(u4.w, xv[q].w, a);
        }
        acc[oc] = a;
    }
    if (valid) {
#pragma unroll
        for (int oc = 0; oc < 64; ++oc) out[(ocg * 64 + oc) * 65536 + pix] = acc[oc];
    }
}

// ---------------- launch ----------------
extern "C" void kernel_launch(void* const* d_in, const int* in_sizes, int n_in,
                              void* d_out, int out_size, void* d_ws, size_t ws_size,
                              hipStream_t stream) {
    const float* cF         = (const float*)d_in[0];
    const float* sF         = (const float*)d_in[1];
    const float* content    = (const float*)d_in[2];
    const float* style      = (const float*)d_in[3];
    const int*   cmasks     = (const int*)d_in[4];
    const int*   smasks     = (const int*)d_in[5];
    const float* compress_w = (const float*)d_in[6];
    const float* unzip_w    = (const float*)d_in[8];
    const float* unzip_b    = (const float*)d_in[9];
    const float* s_w1 = (const float*)d_in[10]; const float* s_b1 = (const float*)d_in[11];
    const float* s_w2 = (const float*)d_in[12]; const float* s_b2 = (const float*)d_in[13];
    const float* s_w3 = (const float*)d_in[14]; const float* s_b3 = (const float*)d_in[15];
    const float* s_fcw = (const float*)d_in[16]; const float* s_fcb = (const float*)d_in[17];
    const float* c_w1 = (const float*)d_in[18]; const float* c_b1 = (const float*)d_in[19];
    const float* c_w2 = (const float*)d_in[20]; const float* c_b2 = (const float*)d_in[21];
    const float* c_w3 = (const float*)d_in[22]; const float* c_b3 = (const float*)d_in[23];
    const float* c_fcw = (const float*)d_in[24]; const float* c_fcb = (const float*)d_in[25];
    float* out = (float*)d_out;
    char* ws = (char*)d_ws;
#define WF(o) ((float*)(ws + (o)))
#define WI(o) ((int*)(ws + (o)))

    init_k<<<1, TPB, 0, stream>>>(WI(0), 256);   // counts, active, lcnt, musum
    bits_k<<<256, TPB, 0, stream>>>(cmasks, smasks, WI(OFF_CBITS), WI(OFF_SBITS), WI(OFF_COUNTS));
    bits128_k<<<64, TPB, 0, stream>>>(cmasks, smasks, WI(OFF_CBITS128), WI(OFF_SBITS128), WI(OFF_COUNTS));
    compact_k<<<dim3(9, 2), TPB, 0, stream>>>(WI(OFF_SBITS128), WI(OFF_CBITS128), WI(OFF_IDX));
    smean_k<<<dim3(256, 4), TPB, 0, stream>>>(sF, WI(OFF_SBITS), WF(OFF_SSUM));
    finalize_k<<<1, TPB, 0, stream>>>(WI(OFF_COUNTS), WI(OFF_ACTIVE), WF(OFF_SSUM), WF(OFF_SMEAN));
    rlist_k<<<256, TPB, 0, stream>>>(WI(OFF_CBITS), WI(OFF_ACTIVE), WI(OFF_LCNT), WI(OFF_RLIST));

    // Xc^T (compress)
    wtr_k<<<64, TPB, 0, stream>>>(compress_w, WF(OFF_CWT), 64, 256);
    xgemm_k<<<dim3(256, 4), TPB, 0, stream>>>(cF, WF(OFF_CWT), WF(OFF_XCT));
    muacc_k<<<256, TPB, 0, stream>>>(WF(OFF_XCT), WF(OFF_MUSUM));
    mufin_k<<<1, 64, 0, stream>>>(WF(OFF_MUSUM), WF(OFF_MU));

    // style CNN
    wtr_k<<<7, TPB, 0, stream>>>(s_w1, WF(OFF_W1T), 64, 27);
    wtr_k<<<72, TPB, 0, stream>>>(s_w2, WF(OFF_W2T), 32, 576);
    wtr_k<<<18, TPB, 0, stream>>>(s_w3, WF(OFF_W3T), 16, 288);
    conv1_k<<<dim3(1024, 2), TPB, 0, stream>>>(style, WF(OFF_W1T), s_b1, WF(OFF_F1));
    f2init_k<<<256, TPB, 0, stream>>>(s_b2, WF(OFF_F2));
    conv2p_k<<<dim3(256, 4), TPB, 0, stream>>>(WF(OFF_F1), WF(OFF_W2T), WF(OFF_F2));
    relu2_k<<<2048, TPB, 0, stream>>>(WF(OFF_F2));
    f3init_k<<<64, TPB, 0, stream>>>(s_b3, WF(OFF_F3));
    conv3p_k<<<dim3(64, 4), TPB, 0, stream>>>(WF(OFF_F2), WF(OFF_W3T), WF(OFF_F3));
    pool_k<<<144, TPB, 0, stream>>>(WF(OFF_F3), WI(OFF_IDX), WI(OFF_COUNTS) + 48, WF(OFF_POOLED));

    // content CNN
    wtr_k<<<7, TPB, 0, stream>>>(c_w1, WF(OFF_W1T), 64, 27);
    wtr_k<<<72, TPB, 0, stream>>>(c_w2, WF(OFF_W2T), 32, 576);
    wtr_k<<<18, TPB, 0, stream>>>(c_w3, WF(OFF_W3T), 16, 288);
    conv1_k<<<dim3(1024, 2), TPB, 0, stream>>>(content, WF(OFF_W1T), c_b1, WF(OFF_F1));
    f2init_k<<<256, TPB, 0, stream>>>(c_b2, WF(OFF_F2));
    conv2p_k<<<dim3(256, 4), TPB, 0, stream>>>(WF(OFF_F1), WF(OFF_W2T), WF(OFF_F2));
    relu2_k<<<2048, TPB, 0, stream>>>(WF(OFF_F2));
    f3init_k<<<64, TPB, 0, stream>>>(c_b3, WF(OFF_F3));
    conv3p_k<<<dim3(64, 4), TPB, 0, stream>>>(WF(OFF_F2), WF(OFF_W3T), WF(OFF_F3));
    pool_k<<<144, TPB, 0, stream>>>(WF(OFF_F3), WI(OFF_IDX) + 9 * 16384, WI(OFF_COUNTS) + 32,
                                    WF(OFF_POOLED) + 9 * 4096);

    fc_k<<<dim3(4096, 2), TPB, 0, stream>>>(s_fcw, s_fcb, c_fcw, c_fcb, WF(OFF_POOLED), WF(OFF_M));

    // U_r = unzip_w @ sM_r @ cM_r ; V_r = unzip_b + sMean_r - U_r @ mu
    uprep1_k<<<576, TPB, 0, stream>>>(unzip_w, WF(OFF_M), WF(OFF_P));
    uprep2_k<<<640, TPB, 0, stream>>>(unzip_w, WF(OFF_M), WF(OFF_P), WF(OFF_U));
    uprep3_k<<<10, TPB, 0, stream>>>(WF(OFF_U), WF(OFF_MU), unzip_b, WF(OFF_SMEAN), WF(OFF_V));

    ustage_k<<<dim3(2560, 4), TPB, 0, stream>>>(WF(OFF_XCT), WF(OFF_U), WF(OFF_V),
                                                WI(OFF_LCNT), WI(OFF_RLIST), out);
}

// Round 3
// 1099.940 us; speedup vs baseline: 1.4828x; 1.1095x over previous
//
#include <hip/hip_runtime.h>
#include <math.h>

#define TPB 256
constexpr int YC_STRIDE = 68096;  // 65536 + 10*256 region padding

// ---------------- workspace layout (bytes) ----------------
constexpr size_t OFF_COUNTS   = 0x000000; // 64 ints
constexpr size_t OFF_ACTIVE   = 0x000100; // 1 int
constexpr size_t OFF_LCNT     = 0x000140; // 10 ints
constexpr size_t OFF_RBASE    = 0x000180; // 10 ints
constexpr size_t OFF_MUSUM    = 0x000200; // 64 floats
constexpr size_t OFF_MU       = 0x000400; // 64 floats
constexpr size_t OFF_SSUM     = 0x000800; // float [4][9][256] partials
constexpr size_t OFF_SMEAN    = 0x00A000; // float [10][256]
constexpr size_t OFF_W1T      = 0x00D000; // [27][64]
constexpr size_t OFF_W3T      = 0x00F000; // [288][16]
constexpr size_t OFF_W2T      = 0x014000; // [576][32]
constexpr size_t OFF_CWT      = 0x028000; // [256][64]  compress_w^T
constexpr size_t OFF_POOLED   = 0x040000; // float [2][9][4096]
constexpr size_t OFF_M        = 0x090000; // float [2][9][4096]
constexpr size_t OFF_P        = 0x0E0000; // float [9][256][64]
constexpr size_t OFF_U        = 0x180000; // float [10][256][64]
constexpr size_t OFF_V        = 0x228000; // float [10][256]
constexpr size_t OFF_CBITS    = 0x230000; // int[65536]
constexpr size_t OFF_SBITS    = 0x270000; // int[65536]
constexpr size_t OFF_CBITS128 = 0x2B0000; // int[16384]
constexpr size_t OFF_SBITS128 = 0x2C0000; // int[16384]
constexpr size_t OFF_IDX      = 0x2D0000; // int [2][9][16384]
constexpr size_t OFF_BC       = 0x3F8000; // int [256][10]
constexpr size_t OFF_BBASE    = 0x400000; // int [256][10]
constexpr size_t OFF_RLIST    = 0x410000; // int [YC_STRIDE]
constexpr size_t OFF_INV      = 0x460000; // int [65536]
constexpr size_t OFF_XCT      = 0x700000; // float [65536][64]  Xc^T
constexpr size_t OFF_F1       = 0x1700000; // float [64][512][512]
constexpr size_t OFF_F2       = 0x5700000; // float [32][256][256]
constexpr size_t OFF_F3       = 0x5F00000; // float [16][128][128]
constexpr size_t OFF_YC       = OFF_F1;    // float [256][YC_STRIDE] (reuses dead F1+F2)

__global__ void init_k(int* p, int n) {
    for (int i = blockIdx.x * TPB + threadIdx.x; i < n; i += gridDim.x * TPB) p[i] = 0;
}

// ---------------- mask bit planes + counts ----------------
__global__ void bits_k(const int* __restrict__ cm, const int* __restrict__ sm,
                       int* __restrict__ cbits, int* __restrict__ sbits, int* __restrict__ counts) {
    int p = blockIdx.x * TPB + threadIdx.x;
    int cb = 0, sb = 0;
#pragma unroll
    for (int r = 0; r < 9; ++r) {
        cb |= (cm[r * 65536 + p] == 1) << r;
        sb |= (sm[r * 65536 + p] == 1) << r;
    }
    cbits[p] = cb; sbits[p] = sb;
    int lane = threadIdx.x & 63;
#pragma unroll
    for (int r = 0; r < 9; ++r) {
        unsigned long long b1 = __ballot((cb >> r) & 1);
        if (lane == 0) atomicAdd(&counts[0 + r], __popcll(b1));
        unsigned long long b2 = __ballot((sb >> r) & 1);
        if (lane == 0) atomicAdd(&counts[16 + r], __popcll(b2));
    }
}

__global__ void bits128_k(const int* __restrict__ cm, const int* __restrict__ sm,
                          int* __restrict__ cbits128, int* __restrict__ sbits128, int* __restrict__ counts) {
    int p = blockIdx.x * TPB + threadIdx.x;
    int y = p >> 7, x = p & 127;
    int src = (2 * y) * 256 + 2 * x;
    int cb = 0, sb = 0;
#pragma unroll
    for (int r = 0; r < 9; ++r) {
        cb |= (cm[r * 65536 + src] == 1) << r;
        sb |= (sm[r * 65536 + src] == 1) << r;
    }
    cbits128[p] = cb; sbits128[p] = sb;
    int lane = threadIdx.x & 63;
#pragma unroll
    for (int r = 0; r < 9; ++r) {
        unsigned long long b1 = __ballot((cb >> r) & 1);
        if (lane == 0) atomicAdd(&counts[32 + r], __popcll(b1));
        unsigned long long b2 = __ballot((sb >> r) & 1);
        if (lane == 0) atomicAdd(&counts[48 + r], __popcll(b2));
    }
}

// ---------------- ordered compaction at 128x128 (ballot scan, 2 barriers/chunk) -----
__global__ void compact_k(const int* __restrict__ sbits128, const int* __restrict__ cbits128,
                          int* __restrict__ idxlist) {
    int r = blockIdx.x, side = blockIdx.y;
    const int* bits = side ? cbits128 : sbits128;
    int* outp = idxlist + (side * 9 + r) * 16384;
    __shared__ int wcnt[4];
    __shared__ int base_s;
    int t = threadIdx.x, w = t >> 6, lane = t & 63;
    if (t == 0) base_s = 0;
    __syncthreads();
    for (int chunk = 0; chunk < 64; ++chunk) {
        int pid = chunk * 256 + t;
        int flag = (bits[pid] >> r) & 1;
        unsigned long long m = __ballot(flag);
        if (lane == 0) wcnt[w] = __popcll(m);
        __syncthreads();
        int base = base_s;
        int woff = 0;
        for (int w2 = 0; w2 < w; ++w2) woff += wcnt[w2];
        if (flag) outp[base + woff + __popcll(m & ((1ull << lane) - 1ull))] = pid;
        __syncthreads();
        if (t == 0) base_s = base + wcnt[0] + wcnt[1] + wcnt[2] + wcnt[3];
    }
}

// ---------------- weight transpose [oc][ick] -> [ick][oc] ----------------
__global__ void wtr_k(const float* __restrict__ w, float* __restrict__ wT, int OC, int ICK) {
    int i = blockIdx.x * TPB + threadIdx.x;
    int n = OC * ICK;
    if (i < n) {
        int oc = i / ICK;
        int t = i - oc * ICK;
        wT[t * OC + oc] = w[i];
    }
}

// ---------------- per-region style mean partial sums ----------------
__global__ void smean_k(const float* __restrict__ sF, const int* __restrict__ sbits,
                        float* __restrict__ ssump) {
    int c = blockIdx.x;
    int pg = blockIdx.y;
    int t = threadIdx.x;
    float acc[9];
#pragma unroll
    for (int r = 0; r < 9; ++r) acc[r] = 0.f;
    int p0 = pg * 16384;
    for (int p = p0 + t; p < p0 + 16384; p += TPB) {
        float v = sF[c * 65536 + p];
        int b = sbits[p];
#pragma unroll
        for (int r = 0; r < 9; ++r)
            if (b & (1 << r)) acc[r] += v;
    }
    __shared__ float red[9 * TPB];
#pragma unroll
    for (int r = 0; r < 9; ++r) red[r * TPB + t] = acc[r];
    __syncthreads();
    for (int off = TPB / 2; off > 0; off >>= 1) {
        if (t < off)
#pragma unroll
            for (int r = 0; r < 9; ++r) red[r * TPB + t] += red[r * TPB + t + off];
        __syncthreads();
    }
    if (t < 9) ssump[(pg * 9 + t) * 256 + c] = red[t * TPB];
}

// ---------------- active mask + per-region style means ----------------
__global__ void finalize_k(const int* __restrict__ counts, int* __restrict__ activemask,
                           const float* __restrict__ ssump, float* __restrict__ sMeanArr) {
    __shared__ int am;
    if (threadIdx.x == 0) am = 0;
    __syncthreads();
    if (threadIdx.x < 9) {
        int r = threadIdx.x;
        if (counts[0 + r] >= 10 && counts[16 + r] >= 10 && counts[32 + r] >= 10 && counts[48 + r] >= 10)
            atomicOr(&am, 1 << r);
    }
    __syncthreads();
    if (threadIdx.x == 0) *activemask = am;
    for (int e = threadIdx.x; e < 2560; e += TPB) {
        int r = e >> 8, c = e & 255;
        float v = 0.f;
        if (r < 9 && ((am >> r) & 1)) {
            float s = ssump[(0 * 9 + r) * 256 + c] + ssump[(1 * 9 + r) * 256 + c]
                    + ssump[(2 * 9 + r) * 256 + c] + ssump[(3 * 9 + r) * 256 + c];
            v = s / (float)counts[16 + r];
        }
        sMeanArr[e] = v;
    }
}

// ---------------- stable region ranking at 256-res: hist -> scan -> rank -------------
__global__ void hist_k(const int* __restrict__ cbits, const int* __restrict__ activemask,
                       int* __restrict__ rmap, int* __restrict__ bc) {
    int b = blockIdx.x, t = threadIdx.x;
    int p = b * 256 + t;
    int am = *activemask;
    int bits = cbits[p] & am;
    int r = bits ? (31 - __clz(bits)) : 9;
    rmap[p] = r;
    __shared__ int wc[4][10];
    int w = t >> 6, lane = t & 63;
#pragma unroll
    for (int rr = 0; rr < 10; ++rr) {
        unsigned long long m = __ballot(r == rr);
        if (lane == rr) wc[w][rr] = __popcll(m);
    }
    __syncthreads();
    if (t < 10) bc[b * 10 + t] = wc[0][t] + wc[1][t] + wc[2][t] + wc[3][t];
}

__global__ void scan_k(const int* __restrict__ bc, int* __restrict__ bbase,
                       int* __restrict__ lcnt, int* __restrict__ rbase) {
    __shared__ int tot[10], Bs[16];
    int t = threadIdx.x;
    if (t < 10) {
        int s = 0;
        for (int b = 0; b < 256; ++b) s += bc[b * 10 + t];
        tot[t] = s;
    }
    __syncthreads();
    if (t == 0) {
        int run = 0;
        for (int r = 0; r < 10; ++r) { Bs[r] = run; run += (tot[r] + 255) & ~255; }
    }
    __syncthreads();
    if (t < 10) {
        lcnt[t] = tot[t];
        rbase[t] = Bs[t];
        int run = Bs[t];
        for (int b = 0; b < 256; ++b) { bbase[b * 10 + t] = run; run += bc[b * 10 + t]; }
    }
}

__global__ void rank_k(const int* __restrict__ rmap, const int* __restrict__ bbase,
                       int* __restrict__ inv, int* __restrict__ rlist) {
    int b = blockIdx.x, t = threadIdx.x;
    int p = b * 256 + t;
    int r = rmap[p];
    __shared__ int wc[4][10];
    int w = t >> 6, lane = t & 63;
    int prefix = 0;
#pragma unroll
    for (int rr = 0; rr < 10; ++rr) {
        unsigned long long m = __ballot(r == rr);
        if (rr == r) prefix = __popcll(m & ((1ull << lane) - 1ull));
        if (lane == rr) wc[w][rr] = __popcll(m);
    }
    __syncthreads();
    int woff = 0;
    for (int w2 = 0; w2 < w; ++w2) woff += wc[w2][r];
    int g = bbase[b * 10 + r] + woff + prefix;
    inv[p] = g;
    rlist[g] = p;
}

// ---------------- conv1: 1024x1024x3 -> 512x512x64, oc-split 2 ----------------
__global__ void conv1_k(const float* __restrict__ in, const float* __restrict__ wT,
                        const float* __restrict__ b, float* __restrict__ out) {
    int idx = blockIdx.x * TPB + threadIdx.x;
    int og = blockIdx.y;
    int ox = idx & 511, oy = idx >> 9;
    float acc[32];
#pragma unroll
    for (int oc = 0; oc < 32; ++oc) acc[oc] = b[og * 32 + oc];
    for (int ic = 0; ic < 3; ++ic)
#pragma unroll
        for (int ky = 0; ky < 3; ++ky) {
            int iy = 2 * oy - 1 + ky;
            if ((unsigned)iy < 1024u)
#pragma unroll
                for (int kx = 0; kx < 3; ++kx) {
                    int ix = 2 * ox - 1 + kx;
                    if ((unsigned)ix < 1024u) {
                        float v = in[ic * 1048576 + iy * 1024 + ix];
                        const float4* wp = (const float4*)(wT + (ic * 9 + ky * 3 + kx) * 64 + og * 32);
#pragma unroll
                        for (int q = 0; q < 8; ++q) {
                            float4 w4 = wp[q];
                            acc[q * 4 + 0] = fmaf(w4.x, v, acc[q * 4 + 0]);
                            acc[q * 4 + 1] = fmaf(w4.y, v, acc[q * 4 + 1]);
                            acc[q * 4 + 2] = fmaf(w4.z, v, acc[q * 4 + 2]);
                            acc[q * 4 + 3] = fmaf(w4.w, v, acc[q * 4 + 3]);
                        }
                    }
                }
        }
#pragma unroll
    for (int oc = 0; oc < 32; ++oc) out[(og * 32 + oc) * 262144 + idx] = fmaxf(acc[oc], 0.f);
}

// ---------------- conv2: bias init, ic-split-4 atomic partials, relu ----------------
__global__ void f2init_k(const float* __restrict__ b, float* __restrict__ F2) {
    int idx = blockIdx.x * TPB + threadIdx.x;
#pragma unroll
    for (int oc = 0; oc < 32; ++oc) F2[oc * 65536 + idx] = b[oc];
}

__global__ void conv2p_k(const float* __restrict__ in, const float* __restrict__ wT,
                         float* __restrict__ F2) {
    int idx = blockIdx.x * TPB + threadIdx.x;
    int icg = blockIdx.y;
    int ox = idx & 255, oy = idx >> 8;
    float acc[32];
#pragma unroll
    for (int oc = 0; oc < 32; ++oc) acc[oc] = 0.f;
    for (int ic = icg * 16; ic < icg * 16 + 16; ++ic) {
        const float* base = in + ic * 262144;
#pragma unroll
        for (int ky = 0; ky < 3; ++ky) {
            int iy = 2 * oy - 1 + ky;
            if ((unsigned)iy < 512u)
#pragma unroll
                for (int kx = 0; kx < 3; ++kx) {
                    int ix = 2 * ox - 1 + kx;
                    if ((unsigned)ix < 512u) {
                        float v = base[iy * 512 + ix];
                        const float4* wp = (const float4*)(wT + (ic * 9 + ky * 3 + kx) * 32);
#pragma unroll
                        for (int q = 0; q < 8; ++q) {
                            float4 w4 = wp[q];
                            acc[q * 4 + 0] = fmaf(w4.x, v, acc[q * 4 + 0]);
                            acc[q * 4 + 1] = fmaf(w4.y, v, acc[q * 4 + 1]);
                            acc[q * 4 + 2] = fmaf(w4.z, v, acc[q * 4 + 2]);
                            acc[q * 4 + 3] = fmaf(w4.w, v, acc[q * 4 + 3]);
                        }
                    }
                }
        }
    }
#pragma unroll
    for (int oc = 0; oc < 32; ++oc) atomicAdd(&F2[oc * 65536 + idx], acc[oc]);
}

__global__ void relu2_k(float* __restrict__ F2) {
    int i = blockIdx.x * TPB + threadIdx.x;
    float4* p = (float4*)F2;
    float4 v = p[i];
    v.x = fmaxf(v.x, 0.f); v.y = fmaxf(v.y, 0.f);
    v.z = fmaxf(v.z, 0.f); v.w = fmaxf(v.w, 0.f);
    p[i] = v;
}

// ---------------- conv3: bias init + ic-split-4 atomic partials (no relu) ------------
__global__ void f3init_k(const float* __restrict__ b, float* __restrict__ F3) {
    int idx = blockIdx.x * TPB + threadIdx.x;
#pragma unroll
    for (int oc = 0; oc < 16; ++oc) F3[oc * 16384 + idx] = b[oc];
}

__global__ void conv3p_k(const float* __restrict__ in, const float* __restrict__ wT,
                         float* __restrict__ F3) {
    int idx = blockIdx.x * TPB + threadIdx.x;
    int icg = blockIdx.y;
    int ox = idx & 127, oy = idx >> 7;
    float acc[16];
#pragma unroll
    for (int oc = 0; oc < 16; ++oc) acc[oc] = 0.f;
    for (int ic = icg * 8; ic < icg * 8 + 8; ++ic) {
        const float* base = in + ic * 65536;
#pragma unroll
        for (int ky = 0; ky < 3; ++ky) {
            int iy = 2 * oy - 1 + ky;
            if ((unsigned)iy < 256u)
#pragma unroll
                for (int kx = 0; kx < 3; ++kx) {
                    int ix = 2 * ox - 1 + kx;
                    if ((unsigned)ix < 256u) {
                        float v = base[iy * 256 + ix];
                        const float4* wp = (const float4*)(wT + (ic * 9 + ky * 3 + kx) * 16);
#pragma unroll
                        for (int q = 0; q < 4; ++q) {
                            float4 w4 = wp[q];
                            acc[q * 4 + 0] = fmaf(w4.x, v, acc[q * 4 + 0]);
                            acc[q * 4 + 1] = fmaf(w4.y, v, acc[q * 4 + 1]);
                            acc[q * 4 + 2] = fmaf(w4.z, v, acc[q * 4 + 2]);
                            acc[q * 4 + 3] = fmaf(w4.w, v, acc[q * 4 + 3]);
                        }
                    }
                }
        }
    }
#pragma unroll
    for (int oc = 0; oc < 16; ++oc) atomicAdd(&F3[oc * 16384 + idx], acc[oc]);
}

// ---------------- adaptive max pool over ordered compacted indices ----------------
__global__ void pool_k(const float* __restrict__ f3, const int* __restrict__ idxbase,
                       const int* __restrict__ cnt, float* __restrict__ pooled) {
    int r = blockIdx.x >> 4;
    int c = blockIdx.x & 15;
    int j = threadIdx.x;
    int n = cnt[r];
    float m = 0.f;
    if (n >= 1) {
        int start = (j * n) >> 8;
        int end = ((j + 1) * n + 255) >> 8;
        const int* il = idxbase + r * 16384;
        m = -__builtin_inff();
        for (int t = start; t < end; ++t) m = fmaxf(m, f3[c * 16384 + il[t]]);
    }
    pooled[(r * 16 + c) * 256 + j] = m;
}

// ---------------- FC: M[side][r][row] (9 cols batched per row-block) ----------------
__global__ void fc_k(const float* __restrict__ fcw_s, const float* __restrict__ fcb_s,
                     const float* __restrict__ fcw_c, const float* __restrict__ fcb_c,
                     const float* __restrict__ pooled, float* __restrict__ Mout) {
    int row = blockIdx.x;
    int side = blockIdx.y;
    const float* fcw = side ? fcw_c : fcw_s;
    const float* fcb = side ? fcb_c : fcb_s;
    const float* P = pooled + side * 9 * 4096;
    int t = threadIdx.x;
    float acc[9];
#pragma unroll
    for (int r = 0; r < 9; ++r) acc[r] = 0.f;
    for (int k = t; k < 4096; k += TPB) {
        float w = fcw[row * 4096 + k];
#pragma unroll
        for (int r = 0; r < 9; ++r) acc[r] = fmaf(w, P[r * 4096 + k], acc[r]);
    }
    __shared__ float red[9 * TPB];
#pragma unroll
    for (int r = 0; r < 9; ++r) red[r * TPB + t] = acc[r];
    __syncthreads();
    for (int off = TPB / 2; off > 0; off >>= 1) {
        if (t < off)
#pragma unroll
            for (int r = 0; r < 9; ++r) red[r * TPB + t] += red[r * TPB + t + off];
        __syncthreads();
    }
    if (t < 9) Mout[(side * 9 + t) * 4096 + row] = red[t * TPB] + fcb[row];
}

// ---------------- Xc^T = (compress_w @ cF)^T, m-split 4 ----------------
__global__ void xgemm_k(const float* __restrict__ cF, const float* __restrict__ cwT,
                        float* __restrict__ XcT) {
    int p = blockIdx.x * TPB + threadIdx.x;
    int m0 = blockIdx.y * 16;
    float acc[16];
#pragma unroll
    for (int m = 0; m < 16; ++m) acc[m] = 0.f;
    for (int k0 = 0; k0 < 256; k0 += 4) {
        float xv[4];
#pragma unroll
        for (int i = 0; i < 4; ++i) xv[i] = cF[(k0 + i) * 65536 + p];
#pragma unroll
        for (int i = 0; i < 4; ++i) {
            const float4* wp = (const float4*)(cwT + (k0 + i) * 64 + m0);
#pragma unroll
            for (int q = 0; q < 4; ++q) {
                float4 w4 = wp[q];
                acc[q * 4 + 0] = fmaf(w4.x, xv[i], acc[q * 4 + 0]);
                acc[q * 4 + 1] = fmaf(w4.y, xv[i], acc[q * 4 + 1]);
                acc[q * 4 + 2] = fmaf(w4.z, xv[i], acc[q * 4 + 2]);
                acc[q * 4 + 3] = fmaf(w4.w, xv[i], acc[q * 4 + 3]);
            }
        }
    }
    float4* op = (float4*)(XcT + p * 64 + m0);
#pragma unroll
    for (int q = 0; q < 4; ++q)
        op[q] = make_float4(acc[q * 4 + 0], acc[q * 4 + 1], acc[q * 4 + 2], acc[q * 4 + 3]);
}

// ---------------- mu from Xc^T ----------------
__global__ void muacc_k(const float* __restrict__ XcT, float* __restrict__ musum) {
    int t = threadIdx.x;
    int m = t & 63, sub = t >> 6;
    int p0 = blockIdx.x * 256;
    float a = 0.f;
    for (int i = 0; i < 64; ++i) a += XcT[(p0 + sub + i * 4) * 64 + m];
    __shared__ float red[TPB];
    red[t] = a;
    __syncthreads();
    if (t < 64) atomicAdd(&musum[t], red[t] + red[t + 64] + red[t + 128] + red[t + 192]);
}

__global__ void mufin_k(const float* __restrict__ musum, float* __restrict__ mu) {
    int t = threadIdx.x;
    if (t < 64) mu[t] = musum[t] * (1.f / 65536.f);
}

// ---------------- U/V precompute ----------------
__global__ void uprep1_k(const float* __restrict__ uw, const float* __restrict__ M,
                         float* __restrict__ P) {
    int idx = blockIdx.x * TPB + threadIdx.x;
    int r = idx / 16384;
    int rem = idx & 16383;
    int c = rem >> 6, k = rem & 63;
    float a = 0.f;
#pragma unroll 8
    for (int i = 0; i < 64; ++i) a = fmaf(uw[c * 64 + i], M[r * 4096 + i * 64 + k], a);
    P[idx] = a;
}

__global__ void uprep2_k(const float* __restrict__ uw, const float* __restrict__ M,
                         const float* __restrict__ P, float* __restrict__ U) {
    int idx = blockIdx.x * TPB + threadIdx.x;
    int r = idx / 16384;
    int rem = idx & 16383;
    int c = rem >> 6, j = rem & 63;
    if (r == 9) { U[idx] = uw[c * 64 + j]; return; }
    float a = 0.f;
#pragma unroll 8
    for (int k = 0; k < 64; ++k) a = fmaf(P[r * 16384 + c * 64 + k], M[(9 + r) * 4096 + k * 64 + j], a);
    U[idx] = a;
}

__global__ void uprep3_k(const float* __restrict__ U, const float* __restrict__ mu,
                         const float* __restrict__ uzb, const float* __restrict__ sMeanArr,
                         float* __restrict__ V) {
    int r = blockIdx.x;
    int c = threadIdx.x;
    float a = uzb[c] + sMeanArr[r * 256 + c];
#pragma unroll 8
    for (int j = 0; j < 64; ++j) a -= U[r * 16384 + c * 64 + j] * mu[j];
    V[r * 256 + c] = a;
}

// ---------------- Yc[oc][rank] = U_r @ Xc + V_r  (coalesced full-line writes) --------
__global__ void ygemm_k(const float* __restrict__ XcT, const float* __restrict__ U,
                        const float* __restrict__ V, const int* __restrict__ lcnt,
                        const int* __restrict__ rbase, const int* __restrict__ rlist,
                        float* __restrict__ Yc) {
    int r = blockIdx.x >> 8;
    int c = blockIdx.x & 255;
    int ocg = blockIdx.y;
    int n = lcnt[r];
    int start = c * 256;
    if (start >= n) return;
    int i = start + threadIdx.x;
    bool valid = i < n;
    int gi = rbase[r] + (valid ? i : n - 1);
    int pix = rlist[gi];
    float4 xv[16];
    const float4* xp = (const float4*)(XcT + (size_t)pix * 64);
#pragma unroll
    for (int q = 0; q < 16; ++q) xv[q] = xp[q];
    const float* Ur = U + r * 16384 + ocg * 4096;
    const float* Vr = V + r * 256 + ocg * 64;
#pragma unroll 4
    for (int oc = 0; oc < 64; ++oc) {
        float a = Vr[oc];
        const float4* up = (const float4*)(Ur + oc * 64);
#pragma unroll
        for (int q = 0; q < 16; ++q) {
            float4 u4 = up[q];
            a = fmaf(u4.x, xv[q].x, a);
            a = fmaf(u4.y, xv[q].y, a);
            a = fmaf(u4.z, xv[q].z, a);
            a = fmaf(u4.w, xv[q].w, a);
        }
        if (valid) Yc[(size_t)(ocg * 64 + oc) * YC_STRIDE + gi] = a;   // store now: no acc[], no spill
    }
}

// ---------------- merge: out[oc][p] = Yc[oc][inv[p]]  (coalesced output writes) ------
__global__ void merge_k(const float* __restrict__ Yc, const int* __restrict__ inv,
                        float* __restrict__ out) {
    int p = blockIdx.x * TPB + threadIdx.x;
    int oc0 = blockIdx.y * 4;
    int gi = inv[p];
#pragma unroll
    for (int j = 0; j < 4; ++j)
        out[(size_t)(oc0 + j) * 65536 + p] = Yc[(size_t)(oc0 + j) * YC_STRIDE + gi];
}

// ---------------- launch ----------------
extern "C" void kernel_launch(void* const* d_in, const int* in_sizes, int n_in,
                              void* d_out, int out_size, void* d_ws, size_t ws_size,
                              hipStream_t stream) {
    const float* cF         = (const float*)d_in[0];
    const float* sF         = (const float*)d_in[1];
    const float* content    = (const float*)d_in[2];
    const float* style      = (const float*)d_in[3];
    const int*   cmasks     = (const int*)d_in[4];
    const int*   smasks     = (const int*)d_in[5];
    const float* compress_w = (const float*)d_in[6];
    const float* unzip_w    = (const float*)d_in[8];
    const float* unzip_b    = (const float*)d_in[9];
    const float* s_w1 = (const float*)d_in[10]; const float* s_b1 = (const float*)d_in[11];
    const float* s_w2 = (const float*)d_in[12]; const float* s_b2 = (const float*)d_in[13];
    const float* s_w3 = (const float*)d_in[14]; const float* s_b3 = (const float*)d_in[15];
    const float* s_fcw = (const float*)d_in[16]; const float* s_fcb = (const float*)d_in[17];
    const float* c_w1 = (const float*)d_in[18]; const float* c_b1 = (const float*)d_in[19];
    const float* c_w2 = (const float*)d_in[20]; const float* c_b2 = (const float*)d_in[21];
    const float* c_w3 = (const float*)d_in[22]; const float* c_b3 = (const float*)d_in[23];
    const float* c_fcw = (const float*)d_in[24]; const float* c_fcb = (const float*)d_in[25];
    float* out = (float*)d_out;
    char* ws = (char*)d_ws;
#define WF(o) ((float*)(ws + (o)))
#define WI(o) ((int*)(ws + (o)))

    init_k<<<1, TPB, 0, stream>>>(WI(0), 256);   // counts, active, musum
    bits_k<<<256, TPB, 0, stream>>>(cmasks, smasks, WI(OFF_CBITS), WI(OFF_SBITS), WI(OFF_COUNTS));
    bits128_k<<<64, TPB, 0, stream>>>(cmasks, smasks, WI(OFF_CBITS128), WI(OFF_SBITS128), WI(OFF_COUNTS));
    compact_k<<<dim3(9, 2), TPB, 0, stream>>>(WI(OFF_SBITS128), WI(OFF_CBITS128), WI(OFF_IDX));
    smean_k<<<dim3(256, 4), TPB, 0, stream>>>(sF, WI(OFF_SBITS), WF(OFF_SSUM));
    finalize_k<<<1, TPB, 0, stream>>>(WI(OFF_COUNTS), WI(OFF_ACTIVE), WF(OFF_SSUM), WF(OFF_SMEAN));

    // stable region ranking
    hist_k<<<256, TPB, 0, stream>>>(WI(OFF_CBITS), WI(OFF_ACTIVE), WI(OFF_INV) /*tmp rmap*/, WI(OFF_BC));
    scan_k<<<1, TPB, 0, stream>>>(WI(OFF_BC), WI(OFF_BBASE), WI(OFF_LCNT), WI(OFF_RBASE));
    rank_k<<<256, TPB, 0, stream>>>(WI(OFF_INV) /*rmap in*/, WI(OFF_BBASE), WI(OFF_INV), WI(OFF_RLIST));

    // Xc^T (compress)
    wtr_k<<<64, TPB, 0, stream>>>(compress_w, WF(OFF_CWT), 64, 256);
    xgemm_k<<<dim3(256, 4), TPB, 0, stream>>>(cF, WF(OFF_CWT), WF(OFF_XCT));
    muacc_k<<<256, TPB, 0, stream>>>(WF(OFF_XCT), WF(OFF_MUSUM));
    mufin_k<<<1, 64, 0, stream>>>(WF(OFF_MUSUM), WF(OFF_MU));

    // style CNN
    wtr_k<<<7, TPB, 0, stream>>>(s_w1, WF(OFF_W1T), 64, 27);
    wtr_k<<<72, TPB, 0, stream>>>(s_w2, WF(OFF_W2T), 32, 576);
    wtr_k<<<18, TPB, 0, stream>>>(s_w3, WF(OFF_W3T), 16, 288);
    conv1_k<<<dim3(1024, 2), TPB, 0, stream>>>(style, WF(OFF_W1T), s_b1, WF(OFF_F1));
    f2init_k<<<256, TPB, 0, stream>>>(s_b2, WF(OFF_F2));
    conv2p_k<<<dim3(256, 4), TPB, 0, stream>>>(WF(OFF_F1), WF(OFF_W2T), WF(OFF_F2));
    relu2_k<<<2048, TPB, 0, stream>>>(WF(OFF_F2));
    f3init_k<<<64, TPB, 0, stream>>>(s_b3, WF(OFF_F3));
    conv3p_k<<<dim3(64, 4), TPB, 0, stream>>>(WF(OFF_F2), WF(OFF_W3T), WF(OFF_F3));
    pool_k<<<144, TPB, 0, stream>>>(WF(OFF_F3), WI(OFF_IDX), WI(OFF_COUNTS) + 48, WF(OFF_POOLED));

    // content CNN
    wtr_k<<<7, TPB, 0, stream>>>(c_w1, WF(OFF_W1T), 64, 27);
    wtr_k<<<72, TPB, 0, stream>>>(c_w2, WF(OFF_W2T), 32, 576);
    wtr_k<<<18, TPB, 0, stream>>>(c_w3, WF(OFF_W3T), 16, 288);
    conv1_k<<<dim3(1024, 2), TPB, 0, stream>>>(content, WF(OFF_W1T), c_b1, WF(OFF_F1));
    f2init_k<<<256, TPB, 0, stream>>>(c_b2, WF(OFF_F2));
    conv2p_k<<<dim3(256, 4), TPB, 0, stream>>>(WF(OFF_F1), WF(OFF_W2T), WF(OFF_F2));
    relu2_k<<<2048, TPB, 0, stream>>>(WF(OFF_F2));
    f3init_k<<<64, TPB, 0, stream>>>(c_b3, WF(OFF_F3));
    conv3p_k<<<dim3(64, 4), TPB, 0, stream>>>(WF(OFF_F2), WF(OFF_W3T), WF(OFF_F3));
    pool_k<<<144, TPB, 0, stream>>>(WF(OFF_F3), WI(OFF_IDX) + 9 * 16384, WI(OFF_COUNTS) + 32,
                                    WF(OFF_POOLED) + 9 * 4096);

    fc_k<<<dim3(4096, 2), TPB, 0, stream>>>(s_fcw, s_fcb, c_fcw, c_fcb, WF(OFF_POOLED), WF(OFF_M));

    uprep1_k<<<576, TPB, 0, stream>>>(unzip_w, WF(OFF_M), WF(OFF_P));
    uprep2_k<<<640, TPB, 0, stream>>>(unzip_w, WF(OFF_M), WF(OFF_P), WF(OFF_U));
    uprep3_k<<<10, TPB, 0, stream>>>(WF(OFF_U), WF(OFF_MU), unzip_b, WF(OFF_SMEAN), WF(OFF_V));

    // final GEMM into rank-compacted Yc (reuses F1/F2 space), then dense merge
    ygemm_k<<<dim3(2560, 4), TPB, 0, stream>>>(WF(OFF_XCT), WF(OFF_U), WF(OFF_V),
                                               WI(OFF_LCNT), WI(OFF_RBASE), WI(OFF_RLIST), WF(OFF_YC));
    merge_k<<<dim3(256, 64), TPB, 0, stream>>>(WF(OFF_YC), WI(OFF_INV), out);
}